// Round 16
// baseline (143.346 us; speedup 1.0000x reference)
//
#include <hip/hip_runtime.h>

#define IN_CH 16
#define OUT_CH 16
#define EDGE_FEAT 32
#define HIDDEN 128
#define WROW 256          // IN_CH*OUT_CH
#define FN_FPB 16         // filters per block in filter-net kernel
#define WSLOTS 64         // per-wave run slots (per tile)
#define LSTR 16           // LDS floats per slot (16 channels; deg derived)

typedef __fp16 half2_v __attribute__((ext_vector_type(2)));
typedef unsigned uvec4 __attribute__((ext_vector_type(4)));
typedef float fvec4 __attribute__((ext_vector_type(4)));

__device__ __forceinline__ unsigned pk_f16(float lo, float hi) {
  half2_v h = __builtin_amdgcn_cvt_pkrtz(lo, hi);
  return __builtin_bit_cast(unsigned, h);
}

__device__ __forceinline__ float dot2(unsigned wpair, half2_v xp, float acc) {
  half2_v w = __builtin_bit_cast(half2_v, wpair);
#if __has_builtin(__builtin_amdgcn_fdot2)
  return __builtin_amdgcn_fdot2(xp, w, acc, false);
#else
  acc = fmaf((float)xp[0], (float)w[0], acc);
  return fmaf((float)xp[1], (float)w[1], acc);
#endif
}

// ---------------- Kernel 1: filter net v2 (r14, measured) -------------------
__global__ __launch_bounds__(256) void filter_net_kernel(
    const float* __restrict__ ef, const float* __restrict__ W1,
    const float* __restrict__ b1, const float* __restrict__ W2,
    const float* __restrict__ b2, unsigned short* __restrict__ weights,
    float* __restrict__ zero_base, int nzero4) {
  const int t = threadIdx.x;
  const int f0 = blockIdx.x * FN_FPB;

  for (int gid = blockIdx.x * 256 + t; gid < nzero4; gid += gridDim.x * 256)
    ((float4*)zero_base)[gid] = make_float4(0.f, 0.f, 0.f, 0.f);

  __shared__ float ef_s[FN_FPB * EDGE_FEAT];   // 2 KB
  __shared__ float h_s[FN_FPB][HIDDEN];        // 8 KB
  ef_s[t] = ef[f0 * EDGE_FEAT + t];
  ef_s[t + 256] = ef[f0 * EDGE_FEAT + t + 256];
  __syncthreads();

  {
    const int hi = t & 127;
    const int fb = (t >> 7) * 8;
    float a[8];
    #pragma unroll
    for (int r = 0; r < 8; ++r) a[r] = b1[hi];
    for (int k0 = 0; k0 < EDGE_FEAT; k0 += 4) {
      float w1v[4];
      #pragma unroll
      for (int m = 0; m < 4; ++m) w1v[m] = W1[(k0 + m) * HIDDEN + hi];
      #pragma unroll
      for (int r = 0; r < 8; ++r) {
        const float4 e4 = *(const float4*)&ef_s[(fb + r) * EDGE_FEAT + k0];
        a[r] = fmaf(e4.x, w1v[0], a[r]);
        a[r] = fmaf(e4.y, w1v[1], a[r]);
        a[r] = fmaf(e4.z, w1v[2], a[r]);
        a[r] = fmaf(e4.w, w1v[3], a[r]);
      }
    }
    #pragma unroll
    for (int r = 0; r < 8; ++r) h_s[fb + r][hi] = a[r] > 0.f ? a[r] : 0.f;
  }
  __syncthreads();

  const int cq = t & 63;
  const int grp = t >> 6;
  float4 facc[4];
  const float4 bb = *(const float4*)(b2 + 4 * cq);
  #pragma unroll
  for (int q = 0; q < 4; ++q) facc[q] = bb;
  for (int k0 = 0; k0 < HIDDEN; k0 += 4) {
    float4 w2v[4];
    #pragma unroll
    for (int m = 0; m < 4; ++m)
      w2v[m] = ((const float4*)(W2 + (size_t)(k0 + m) * WROW))[cq];
    #pragma unroll
    for (int q = 0; q < 4; ++q) {
      const float4 h4 = *(const float4*)&h_s[grp * 4 + q][k0];
      facc[q].x = fmaf(h4.x, w2v[0].x, facc[q].x);
      facc[q].y = fmaf(h4.x, w2v[0].y, facc[q].y);
      facc[q].z = fmaf(h4.x, w2v[0].z, facc[q].z);
      facc[q].w = fmaf(h4.x, w2v[0].w, facc[q].w);
      facc[q].x = fmaf(h4.y, w2v[1].x, facc[q].x);
      facc[q].y = fmaf(h4.y, w2v[1].y, facc[q].y);
      facc[q].z = fmaf(h4.y, w2v[1].z, facc[q].z);
      facc[q].w = fmaf(h4.y, w2v[1].w, facc[q].w);
      facc[q].x = fmaf(h4.z, w2v[2].x, facc[q].x);
      facc[q].y = fmaf(h4.z, w2v[2].y, facc[q].y);
      facc[q].z = fmaf(h4.z, w2v[2].z, facc[q].z);
      facc[q].w = fmaf(h4.z, w2v[2].w, facc[q].w);
      facc[q].x = fmaf(h4.w, w2v[3].x, facc[q].x);
      facc[q].y = fmaf(h4.w, w2v[3].y, facc[q].y);
      facc[q].z = fmaf(h4.w, w2v[3].z, facc[q].z);
      facc[q].w = fmaf(h4.w, w2v[3].w, facc[q].w);
    }
  }

  const int i = cq >> 2;
  const int jo = cq & 3;
  const int u = i >> 1;
  #pragma unroll
  for (int q = 0; q < 4; ++q) {
    float4 oth;
    oth.x = __shfl_xor(facc[q].x, 4);
    oth.y = __shfl_xor(facc[q].y, 4);
    oth.z = __shfl_xor(facc[q].z, 4);
    oth.w = __shfl_xor(facc[q].w, 4);
    if ((i & 1) == 0) {
      uint4 st;
      st.x = pk_f16(facc[q].x, oth.x);
      st.y = pk_f16(facc[q].y, oth.y);
      st.z = pk_f16(facc[q].z, oth.z);
      st.w = pk_f16(facc[q].w, oth.w);
      *(uint4*)(weights + (size_t)(f0 + grp * 4 + q) * WROW +
                (u * 4 + jo) * 8) = st;
    }
  }
}

// ---------------- Kernel 2: two 64-edge tiles per wave ----------------------
template <int CTRL, int OLD>
__device__ __forceinline__ int dpp_i(int v) {
  return __builtin_amdgcn_update_dpp(OLD, v, CTRL, 0xf, 0xf, false);
}
template <int CTRL>
__device__ __forceinline__ float dpp_f(float v) {
  return __builtin_bit_cast(
      float, __builtin_amdgcn_update_dpp(0, __builtin_bit_cast(int, v), CTRL,
                                         0xf, 0xf, false));
}
template <int Q>
__device__ __forceinline__ int quad_bcast_dpp(int v) {
  return __builtin_amdgcn_update_dpp(0, v, Q * 0x55, 0xf, 0xf, false);
}

template <int CTRL>
__device__ __forceinline__ void seg_step_dpp(int sl, fvec4& acc) {
  const int os = dpp_i<CTRL, -1>(sl);
  const float ox = dpp_f<CTRL>(acc.x);
  const float oy = dpp_f<CTRL>(acc.y);
  const float oz = dpp_f<CTRL>(acc.z);
  const float ow = dpp_f<CTRL>(acc.w);
  if (os == sl) {
    acc.x += ox; acc.y += oy; acc.z += oz; acc.w += ow;
  }
}

__device__ __forceinline__ fvec4 edge_dot(const fvec4 xo, const uvec4* wv) {
  const int p0 = (int)pk_f16(xo.x, xo.y);
  const int p1 = (int)pk_f16(xo.z, xo.w);
  half2_v xp[8];
  xp[0] = __builtin_bit_cast(half2_v, quad_bcast_dpp<0>(p0));
  xp[1] = __builtin_bit_cast(half2_v, quad_bcast_dpp<0>(p1));
  xp[2] = __builtin_bit_cast(half2_v, quad_bcast_dpp<1>(p0));
  xp[3] = __builtin_bit_cast(half2_v, quad_bcast_dpp<1>(p1));
  xp[4] = __builtin_bit_cast(half2_v, quad_bcast_dpp<2>(p0));
  xp[5] = __builtin_bit_cast(half2_v, quad_bcast_dpp<2>(p1));
  xp[6] = __builtin_bit_cast(half2_v, quad_bcast_dpp<3>(p0));
  xp[7] = __builtin_bit_cast(half2_v, quad_bcast_dpp<3>(p1));

  fvec4 acc = {0.f, 0.f, 0.f, 0.f};
  #pragma unroll
  for (int u = 0; u < 8; ++u) {
    acc.x = dot2(wv[u].x, xp[u], acc.x);
    acc.y = dot2(wv[u].y, xp[u], acc.y);
    acc.z = dot2(wv[u].z, xp[u], acc.z);
    acc.w = dot2(wv[u].w, xp[u], acc.w);
  }
  return acc;
}

__global__ __launch_bounds__(256) void edge_kernel(
    const float* __restrict__ input, const int* __restrict__ idxn,
    const int* __restrict__ idxe, const int* __restrict__ seg,
    const unsigned short* __restrict__ weights, float* __restrict__ sums,
    float* __restrict__ deg, int n_edges) {
  __shared__ float lds_acc[4][WSLOTS * LSTR];   // 4 x 4 KB (wave-private)
  __shared__ int lds_map[4][WSLOTS];

  const int t = threadIdx.x;
  const int lane = t & 63;
  const int w = t >> 6;
  const int e16 = lane >> 2;
  const int j = lane & 3;
  float* __restrict__ acc_w = lds_acc[w];

  // wave handles 128 consecutive edges as two sequential 64-edge tiles;
  // both tiles' metadata is loaded up front so tile-1's gather can overlap
  // tile-0's scan/flush tail under the compiler's relaxed schedule.
  const long wave_base = (long)blockIdx.x * 512 + w * 128;

  int svv[2], nvv[2], fvv[2];
  #pragma unroll
  for (int tl = 0; tl < 2; ++tl) {
    long el = wave_base + tl * 64 + lane;
    const bool vl = el < n_edges;
    if (!vl) el = n_edges - 1;
    svv[tl] = vl ? seg[el] : -1;
    nvv[tl] = idxn[el];
    fvv[tl] = idxe[el];
  }

  #pragma unroll
  for (int tl = 0; tl < 2; ++tl) {
    const long tb = wave_base + tl * 64;
    long rem = n_edges - tb;
    const int valid_cnt = rem < 0 ? 0 : (rem > 64 ? 64 : (int)rem);
    if (valid_cnt == 0) break;

    const int sv = svv[tl];
    const int n_l = nvv[tl];
    const int f_l = fvv[tl];
    const bool vl = lane < valid_cnt;

    const int sprev = __shfl(sv, (lane - 1) & 63);
    const bool head = vl && (lane == 0 || sprev != sv);
    const unsigned long long bal = __ballot(head);
    const int r = (int)__popcll(bal & ((1ull << lane) - 1ull));
    const int r_w = (int)__popcll(bal);

    for (int idx = lane; idx < r_w * LSTR; idx += 64) acc_w[idx] = 0.f;

    const int slot_l = r - (head ? 0 : 1);
    if (head) lds_map[w][slot_l] = (lane << 20) | sv;  // head lane | node id

    #pragma unroll
    for (int g = 0; g < 4; ++g) {
      const int src = g * 16 + e16;
      const int fg = __shfl(f_l, src);
      const int ng = __shfl(n_l, src);
      const int sl = __shfl(slot_l, src);
      const bool ve = src < valid_cnt;

      const char* __restrict__ wb =
          (const char*)weights + (((size_t)fg << 9) | (j << 4));
      uvec4 wv[8];
      #pragma unroll
      for (int u = 0; u < 8; ++u) wv[u] = *(const uvec4*)(wb + (u << 6));
      const fvec4 xo = *(const fvec4*)(input + ((size_t)ng << 4) + (j << 2));

      fvec4 acc = edge_dot(xo, wv);
      if (!ve) { acc.x = 0.f; acc.y = 0.f; acc.z = 0.f; acc.w = 0.f; }

      seg_step_dpp<0x104>(sl, acc);            // + next edge (within row)
      seg_step_dpp<0x108>(sl, acc);            // + edges +2,+3
      const int pslot = dpp_i<0x114, -1>(sl);  // prev edge's slot
      if (ve && pslot != sl) {                 // sub-run head -> LDS acc
        float* p = acc_w + sl * LSTR + j * 4;
        atomicAdd(p + 0, acc.x);
        atomicAdd(p + 1, acc.y);
        atomicAdd(p + 2, acc.z);
        atomicAdd(p + 3, acc.w);
      }
    }

    // drain wave-local DS before reading slots (no barrier: wave-private).
    asm volatile("s_waitcnt lgkmcnt(0)" ::: "memory");

    const int ch = lane & 15;
    for (int slot = lane >> 4; slot < r_w; slot += 4) {
      const int m0 = lds_map[w][slot];
      const int node = m0 & 0xFFFFF;
      atomicAdd(sums + ((size_t)node << 4) + ch, acc_w[slot * LSTR + ch]);
      if (ch == 0) {
        const int start = m0 >> 20;
        const int end =
            (slot + 1 < r_w) ? (lds_map[w][slot + 1] >> 20) : valid_cnt;
        atomicAdd(deg + node, (float)(end - start));
      }
    }
    // in-order per-wave DS guarantees the flush's LDS reads complete before
    // the next tile's zeroing writes; no extra barrier needed.
  }
}

// ---------------- Kernel 3: divide by degree --------------------------------
__global__ __launch_bounds__(256) void finalize_kernel(
    const float* __restrict__ sums, const float* __restrict__ deg,
    float* __restrict__ out, int n_nodes) {
  const int n = blockIdx.x * blockDim.x + threadIdx.x;
  if (n >= n_nodes) return;
  const float d = deg[n];
  const float scale = d > 0.f ? 1.f / d : 0.f;
  const float4* sp = (const float4*)(sums + (size_t)n * OUT_CH);
  float4* op = (float4*)(out + (size_t)n * OUT_CH);
  #pragma unroll
  for (int q = 0; q < 4; ++q) {
    float4 v = sp[q];
    v.x *= scale; v.y *= scale; v.z *= scale; v.w *= scale;
    op[q] = v;
  }
}

extern "C" void kernel_launch(void* const* d_in, const int* in_sizes, int n_in,
                              void* d_out, int out_size, void* d_ws, size_t ws_size,
                              hipStream_t stream) {
  const float* input = (const float*)d_in[0];
  const int* idxn    = (const int*)d_in[1];
  const int* idxe    = (const int*)d_in[2];
  const int* seg     = (const int*)d_in[3];
  const float* ef    = (const float*)d_in[4];
  const float* W1    = (const float*)d_in[5];
  const float* b1    = (const float*)d_in[6];
  const float* W2    = (const float*)d_in[7];
  const float* b2    = (const float*)d_in[8];
  float* out = (float*)d_out;

  const int n_nodes   = in_sizes[0] / IN_CH;
  const int n_edges   = in_sizes[1];
  const int n_filters = in_sizes[4] / EDGE_FEAT;

  // workspace: f16 weights [F*256] (2 MB) | sums [n_nodes*16] | deg [n_nodes]
  unsigned short* weights = (unsigned short*)d_ws;
  float* sums = (float*)((char*)d_ws + (size_t)n_filters * WROW * sizeof(unsigned short));
  float* deg  = sums + (size_t)n_nodes * OUT_CH;

  const int nzero4 = (n_nodes * (OUT_CH + 1)) / 4;
  filter_net_kernel<<<n_filters / FN_FPB, 256, 0, stream>>>(
      ef, W1, b1, W2, b2, weights, sums, nzero4);

  // 512 edges per block (two 64-edge tiles per wave).
  const long n_blocks = ((long)n_edges + 511) / 512;
  edge_kernel<<<(int)n_blocks, 256, 0, stream>>>(
      input, idxn, idxe, seg, weights, sums, deg, n_edges);

  finalize_kernel<<<(n_nodes + 255) / 256, 256, 0, stream>>>(sums, deg, out,
                                                             n_nodes);
}

// Round 17
// 139.263 us; speedup vs baseline: 1.0293x; 1.0293x over previous
//
#include <hip/hip_runtime.h>

#define IN_CH 16
#define OUT_CH 16
#define EDGE_FEAT 32
#define HIDDEN 128
#define WROW 256          // IN_CH*OUT_CH
#define FN_FPB 16         // filters per block in filter-net kernel
#define WSLOTS 64         // per-wave run slots
#define LSTR 16           // LDS floats per slot (16 channels; deg derived)

typedef __fp16 half2_v __attribute__((ext_vector_type(2)));
typedef unsigned uvec4 __attribute__((ext_vector_type(4)));
typedef float fvec4 __attribute__((ext_vector_type(4)));

__device__ __forceinline__ unsigned pk_f16(float lo, float hi) {
  half2_v h = __builtin_amdgcn_cvt_pkrtz(lo, hi);
  return __builtin_bit_cast(unsigned, h);
}

__device__ __forceinline__ float dot2(unsigned wpair, half2_v xp, float acc) {
  half2_v w = __builtin_bit_cast(half2_v, wpair);
#if __has_builtin(__builtin_amdgcn_fdot2)
  return __builtin_amdgcn_fdot2(xp, w, acc, false);
#else
  acc = fmaf((float)xp[0], (float)w[0], acc);
  return fmaf((float)xp[1], (float)w[1], acc);
#endif
}

// ---------------- Kernel 1: filter net v2 (r14, measured -7 µs) -------------
__global__ __launch_bounds__(256) void filter_net_kernel(
    const float* __restrict__ ef, const float* __restrict__ W1,
    const float* __restrict__ b1, const float* __restrict__ W2,
    const float* __restrict__ b2, unsigned short* __restrict__ weights,
    float* __restrict__ zero_base, int nzero4) {
  const int t = threadIdx.x;
  const int f0 = blockIdx.x * FN_FPB;

  for (int gid = blockIdx.x * 256 + t; gid < nzero4; gid += gridDim.x * 256)
    ((float4*)zero_base)[gid] = make_float4(0.f, 0.f, 0.f, 0.f);

  __shared__ float ef_s[FN_FPB * EDGE_FEAT];   // 2 KB
  __shared__ float h_s[FN_FPB][HIDDEN];        // 8 KB
  ef_s[t] = ef[f0 * EDGE_FEAT + t];
  ef_s[t + 256] = ef[f0 * EDGE_FEAT + t + 256];
  __syncthreads();

  // stage 1: 2048 h values, 8 per thread.
  {
    const int hi = t & 127;
    const int fb = (t >> 7) * 8;
    float a[8];
    #pragma unroll
    for (int r = 0; r < 8; ++r) a[r] = b1[hi];
    for (int k0 = 0; k0 < EDGE_FEAT; k0 += 4) {
      float w1v[4];
      #pragma unroll
      for (int m = 0; m < 4; ++m) w1v[m] = W1[(k0 + m) * HIDDEN + hi];
      #pragma unroll
      for (int r = 0; r < 8; ++r) {
        const float4 e4 = *(const float4*)&ef_s[(fb + r) * EDGE_FEAT + k0];
        a[r] = fmaf(e4.x, w1v[0], a[r]);
        a[r] = fmaf(e4.y, w1v[1], a[r]);
        a[r] = fmaf(e4.z, w1v[2], a[r]);
        a[r] = fmaf(e4.w, w1v[3], a[r]);
      }
    }
    #pragma unroll
    for (int r = 0; r < 8; ++r) h_s[fb + r][hi] = a[r] > 0.f ? a[r] : 0.f;
  }
  __syncthreads();

  // stage 2: cq owns cols 4cq..4cq+3 for filters grp*4..grp*4+3.
  const int cq = t & 63;
  const int grp = t >> 6;
  float4 facc[4];
  const float4 bb = *(const float4*)(b2 + 4 * cq);
  #pragma unroll
  for (int q = 0; q < 4; ++q) facc[q] = bb;
  for (int k0 = 0; k0 < HIDDEN; k0 += 4) {
    float4 w2v[4];
    #pragma unroll
    for (int m = 0; m < 4; ++m)
      w2v[m] = ((const float4*)(W2 + (size_t)(k0 + m) * WROW))[cq];
    #pragma unroll
    for (int q = 0; q < 4; ++q) {
      const float4 h4 = *(const float4*)&h_s[grp * 4 + q][k0];
      facc[q].x = fmaf(h4.x, w2v[0].x, facc[q].x);
      facc[q].y = fmaf(h4.x, w2v[0].y, facc[q].y);
      facc[q].z = fmaf(h4.x, w2v[0].z, facc[q].z);
      facc[q].w = fmaf(h4.x, w2v[0].w, facc[q].w);
      facc[q].x = fmaf(h4.y, w2v[1].x, facc[q].x);
      facc[q].y = fmaf(h4.y, w2v[1].y, facc[q].y);
      facc[q].z = fmaf(h4.y, w2v[1].z, facc[q].z);
      facc[q].w = fmaf(h4.y, w2v[1].w, facc[q].w);
      facc[q].x = fmaf(h4.z, w2v[2].x, facc[q].x);
      facc[q].y = fmaf(h4.z, w2v[2].y, facc[q].y);
      facc[q].z = fmaf(h4.z, w2v[2].z, facc[q].z);
      facc[q].w = fmaf(h4.z, w2v[2].w, facc[q].w);
      facc[q].x = fmaf(h4.w, w2v[3].x, facc[q].x);
      facc[q].y = fmaf(h4.w, w2v[3].y, facc[q].y);
      facc[q].z = fmaf(h4.w, w2v[3].z, facc[q].z);
      facc[q].w = fmaf(h4.w, w2v[3].w, facc[q].w);
    }
  }

  const int i = cq >> 2;
  const int jo = cq & 3;
  const int u = i >> 1;
  #pragma unroll
  for (int q = 0; q < 4; ++q) {
    float4 oth;
    oth.x = __shfl_xor(facc[q].x, 4);
    oth.y = __shfl_xor(facc[q].y, 4);
    oth.z = __shfl_xor(facc[q].z, 4);
    oth.w = __shfl_xor(facc[q].w, 4);
    if ((i & 1) == 0) {
      uint4 st;
      st.x = pk_f16(facc[q].x, oth.x);
      st.y = pk_f16(facc[q].y, oth.y);
      st.z = pk_f16(facc[q].z, oth.z);
      st.w = pk_f16(facc[q].w, oth.w);
      *(uint4*)(weights + (size_t)(f0 + grp * 4 + q) * WROW +
                (u * 4 + jo) * 8) = st;
    }
  }
}

// ---------------- Kernel 2: r15 (measured best: 51 µs) ----------------------
template <int CTRL, int OLD>
__device__ __forceinline__ int dpp_i(int v) {
  return __builtin_amdgcn_update_dpp(OLD, v, CTRL, 0xf, 0xf, false);
}
template <int CTRL>
__device__ __forceinline__ float dpp_f(float v) {
  return __builtin_bit_cast(
      float, __builtin_amdgcn_update_dpp(0, __builtin_bit_cast(int, v), CTRL,
                                         0xf, 0xf, false));
}
template <int Q>
__device__ __forceinline__ int quad_bcast_dpp(int v) {
  return __builtin_amdgcn_update_dpp(0, v, Q * 0x55, 0xf, 0xf, false);
}

template <int CTRL>
__device__ __forceinline__ void seg_step_dpp(int sl, fvec4& acc) {
  const int os = dpp_i<CTRL, -1>(sl);
  const float ox = dpp_f<CTRL>(acc.x);
  const float oy = dpp_f<CTRL>(acc.y);
  const float oz = dpp_f<CTRL>(acc.z);
  const float ow = dpp_f<CTRL>(acc.w);
  if (os == sl) {
    acc.x += ox; acc.y += oy; acc.z += oz; acc.w += ow;
  }
}

__device__ __forceinline__ fvec4 edge_dot(const fvec4 xo, const uvec4* wv) {
  const int p0 = (int)pk_f16(xo.x, xo.y);
  const int p1 = (int)pk_f16(xo.z, xo.w);
  half2_v xp[8];
  xp[0] = __builtin_bit_cast(half2_v, quad_bcast_dpp<0>(p0));
  xp[1] = __builtin_bit_cast(half2_v, quad_bcast_dpp<0>(p1));
  xp[2] = __builtin_bit_cast(half2_v, quad_bcast_dpp<1>(p0));
  xp[3] = __builtin_bit_cast(half2_v, quad_bcast_dpp<1>(p1));
  xp[4] = __builtin_bit_cast(half2_v, quad_bcast_dpp<2>(p0));
  xp[5] = __builtin_bit_cast(half2_v, quad_bcast_dpp<2>(p1));
  xp[6] = __builtin_bit_cast(half2_v, quad_bcast_dpp<3>(p0));
  xp[7] = __builtin_bit_cast(half2_v, quad_bcast_dpp<3>(p1));

  fvec4 acc = {0.f, 0.f, 0.f, 0.f};
  #pragma unroll
  for (int u = 0; u < 8; ++u) {
    acc.x = dot2(wv[u].x, xp[u], acc.x);
    acc.y = dot2(wv[u].y, xp[u], acc.y);
    acc.z = dot2(wv[u].z, xp[u], acc.z);
    acc.w = dot2(wv[u].w, xp[u], acc.w);
  }
  return acc;
}

__global__ __launch_bounds__(256) void edge_kernel(
    const float* __restrict__ input, const int* __restrict__ idxn,
    const int* __restrict__ idxe, const int* __restrict__ seg,
    const unsigned short* __restrict__ weights, float* __restrict__ sums,
    float* __restrict__ deg, int n_edges) {
  __shared__ float lds_acc[4][WSLOTS * LSTR];   // 4 x 4 KB (wave-private)
  __shared__ int lds_map[4][WSLOTS];

  const int t = threadIdx.x;
  const int lane = t & 63;
  const int w = t >> 6;
  const int e16 = lane >> 2;
  const int j = lane & 3;
  float* __restrict__ acc_w = lds_acc[w];

  const long wv_base = (long)blockIdx.x * 256 + w * 64;
  long rem = n_edges - wv_base;
  const int valid_cnt = rem < 0 ? 0 : (rem > 64 ? 64 : (int)rem);

  long el = wv_base + lane;
  const bool vl = el < n_edges;
  if (!vl) el = n_edges - 1;
  const int s_l = seg[el];
  const int n_l = idxn[el];
  const int f_l = idxe[el];
  const int sv = vl ? s_l : -1;

  const int sprev = __shfl(sv, (lane - 1) & 63);
  const bool head = vl && (lane == 0 || sprev != sv);
  const unsigned long long bal = __ballot(head);
  const int r = (int)__popcll(bal & ((1ull << lane) - 1ull));
  const int r_w = (int)__popcll(bal);

  for (int idx = lane; idx < r_w * LSTR; idx += 64) acc_w[idx] = 0.f;

  const int slot_l = r - (head ? 0 : 1);
  if (head) lds_map[w][slot_l] = (lane << 20) | sv;   // head lane | node id

  // 4 phases of 16 edges; relaxed scheduling (the compiler's interleave
  // beat every source-pinned pipeline attempted in r9/r11/r14/r16).
  #pragma unroll
  for (int g = 0; g < 4; ++g) {
    const int src = g * 16 + e16;
    const int fg = __shfl(f_l, src);
    const int ng = __shfl(n_l, src);
    const int sl = __shfl(slot_l, src);
    const bool ve = src < valid_cnt;

    const char* __restrict__ wb =
        (const char*)weights + (((size_t)fg << 9) | (j << 4));
    uvec4 wv[8];
    #pragma unroll
    for (int u = 0; u < 8; ++u) wv[u] = *(const uvec4*)(wb + (u << 6));
    const fvec4 xo = *(const fvec4*)(input + ((size_t)ng << 4) + (j << 2));

    fvec4 acc = edge_dot(xo, wv);
    if (!ve) { acc.x = 0.f; acc.y = 0.f; acc.z = 0.f; acc.w = 0.f; }

    seg_step_dpp<0x104>(sl, acc);            // + next edge (within row)
    seg_step_dpp<0x108>(sl, acc);            // + edges +2,+3
    const int pslot = dpp_i<0x114, -1>(sl);  // prev edge's slot
    if (ve && pslot != sl) {                 // sub-run head -> LDS accumulate
      float* p = acc_w + sl * LSTR + j * 4;
      atomicAdd(p + 0, acc.x);
      atomicAdd(p + 1, acc.y);
      atomicAdd(p + 2, acc.z);
      atomicAdd(p + 3, acc.w);
    }
  }

  // drain wave-local DS before reading slots (no barrier: wave-private).
  asm volatile("s_waitcnt lgkmcnt(0)" ::: "memory");

  // flush; deg derived from head-lane deltas (no cnt accumulation).
  const int ch = lane & 15;
  for (int slot = lane >> 4; slot < r_w; slot += 4) {
    const int m0 = lds_map[w][slot];
    const int node = m0 & 0xFFFFF;
    atomicAdd(sums + ((size_t)node << 4) + ch, acc_w[slot * LSTR + ch]);
    if (ch == 0) {
      const int start = m0 >> 20;
      const int end =
          (slot + 1 < r_w) ? (lds_map[w][slot + 1] >> 20) : valid_cnt;
      atomicAdd(deg + node, (float)(end - start));
    }
  }
}

// ---------------- Kernel 3: divide by degree --------------------------------
__global__ __launch_bounds__(256) void finalize_kernel(
    const float* __restrict__ sums, const float* __restrict__ deg,
    float* __restrict__ out, int n_nodes) {
  const int n = blockIdx.x * blockDim.x + threadIdx.x;
  if (n >= n_nodes) return;
  const float d = deg[n];
  const float scale = d > 0.f ? 1.f / d : 0.f;
  const float4* sp = (const float4*)(sums + (size_t)n * OUT_CH);
  float4* op = (float4*)(out + (size_t)n * OUT_CH);
  #pragma unroll
  for (int q = 0; q < 4; ++q) {
    float4 v = sp[q];
    v.x *= scale; v.y *= scale; v.z *= scale; v.w *= scale;
    op[q] = v;
  }
}

extern "C" void kernel_launch(void* const* d_in, const int* in_sizes, int n_in,
                              void* d_out, int out_size, void* d_ws, size_t ws_size,
                              hipStream_t stream) {
  const float* input = (const float*)d_in[0];
  const int* idxn    = (const int*)d_in[1];
  const int* idxe    = (const int*)d_in[2];
  const int* seg     = (const int*)d_in[3];
  const float* ef    = (const float*)d_in[4];
  const float* W1    = (const float*)d_in[5];
  const float* b1    = (const float*)d_in[6];
  const float* W2    = (const float*)d_in[7];
  const float* b2    = (const float*)d_in[8];
  float* out = (float*)d_out;

  const int n_nodes   = in_sizes[0] / IN_CH;
  const int n_edges   = in_sizes[1];
  const int n_filters = in_sizes[4] / EDGE_FEAT;

  // workspace: f16 weights [F*256] (2 MB) | sums [n_nodes*16] | deg [n_nodes]
  unsigned short* weights = (unsigned short*)d_ws;
  float* sums = (float*)((char*)d_ws + (size_t)n_filters * WROW * sizeof(unsigned short));
  float* deg  = sums + (size_t)n_nodes * OUT_CH;

  const int nzero4 = (n_nodes * (OUT_CH + 1)) / 4;
  filter_net_kernel<<<n_filters / FN_FPB, 256, 0, stream>>>(
      ef, W1, b1, W2, b2, weights, sums, nzero4);

  const long n_blocks = ((long)n_edges + 255) / 256;
  edge_kernel<<<(int)n_blocks, 256, 0, stream>>>(
      input, idxn, idxe, seg, weights, sums, deg, n_edges);

  finalize_kernel<<<(n_nodes + 255) / 256, 256, 0, stream>>>(sums, deg, out,
                                                             n_nodes);
}